// Round 1
// baseline (447.741 us; speedup 1.0000x reference)
//
#include <hip/hip_runtime.h>

// LayoutLMv2 self-attention, MI355X.  B=8 N=1024 H=16 D=64.
// Pipeline: fp32->bf16 converts, bias combine, bf16 MFMA QKV GEMM (m97-style),
// flash attention with online softmax (fp32) + bf16 MFMA.

typedef __bf16 bf16;
typedef __bf16 bf16x8 __attribute__((ext_vector_type(8)));
typedef __bf16 bf16x4 __attribute__((ext_vector_type(4)));
typedef float floatx4 __attribute__((ext_vector_type(4)));

#define MFMA16(a, b, c) __builtin_amdgcn_mfma_f32_16x16x32_bf16((a), (b), (c), 0, 0, 0)

__device__ __forceinline__ void gld16(const bf16* g, bf16* l) {
    // async global->LDS, 16B per lane; LDS dest = uniform base + lane*16
    __builtin_amdgcn_global_load_lds(
        (const __attribute__((address_space(1))) unsigned int*)g,
        (__attribute__((address_space(3))) unsigned int*)l, 16, 0, 0);
}

// ---------------- prep kernels ----------------
__global__ __launch_bounds__(256) void cvt_kernel(const float* __restrict__ x,
                                                  bf16* __restrict__ y, int n4) {
    int i = blockIdx.x * blockDim.x + threadIdx.x;
    if (i >= n4) return;
    float4 v = ((const float4*)x)[i];
    bf16x4 o;
    o.x = (bf16)v.x; o.y = (bf16)v.y; o.z = (bf16)v.z; o.w = (bf16)v.w;
    ((bf16x4*)y)[i] = o;
}

__global__ __launch_bounds__(256) void combine_kernel(const float* __restrict__ a,
                                                      const float* __restrict__ b,
                                                      bf16* __restrict__ y, int n4) {
    int i = blockIdx.x * blockDim.x + threadIdx.x;
    if (i >= n4) return;
    float4 va = ((const float4*)a)[i];
    float4 vb = ((const float4*)b)[i];
    bf16x4 o;
    o.x = (bf16)(va.x + vb.x); o.y = (bf16)(va.y + vb.y);
    o.z = (bf16)(va.z + vb.z); o.w = (bf16)(va.w + vb.w);
    ((bf16x4*)y)[i] = o;
}

// ---------------- QKV GEMM ----------------
// C[m,o] = sum_k X[m,k] * W[o,k];  M=8192, N=3072, K=1024, all bf16, fp32 acc.
// 128x128 tile per block, 4 waves in 2x2, each wave 64x64 (4x4 MFMA tiles), BK=32.
// LDS chunks XOR-swizzled: slot = row*4 + (dc ^ (row&3)).
__global__ __launch_bounds__(256) void qkv_gemm(
    const bf16* __restrict__ X, const bf16* __restrict__ W,
    const float* __restrict__ qbias, const float* __restrict__ vbias,
    bf16* __restrict__ qbuf, bf16* __restrict__ kbuf, bf16* __restrict__ vbuf) {
    __shared__ __align__(16) bf16 Al[128 * 32];
    __shared__ __align__(16) bf16 Bl[128 * 32];

    int tid = threadIdx.x, lane = tid & 63, w = tid >> 6;
    int quad = lane >> 4, lcol = lane & 15;
    int bx = blockIdx.x;  // col tile 0..23
    int by = blockIdx.y;  // row tile 0..63
    int wr = w >> 1, wc = w & 1;

    floatx4 z4 = {0.f, 0.f, 0.f, 0.f};
    floatx4 acc[4][4];
    for (int i = 0; i < 4; ++i)
        for (int j = 0; j < 4; ++j) acc[i][j] = z4;

    const bf16* Ag = X + (size_t)by * 128 * 1024;
    const bf16* Bg = W + (size_t)bx * 128 * 1024;

    for (int kt = 0; kt < 32; ++kt) {
        int k0 = kt * 32;
        __syncthreads();
        for (int j = 0; j < 2; ++j) {
            int c = (w * 2 + j) * 64 + lane;
            int row = c >> 2;
            int dc = (c & 3) ^ (row & 3);
            gld16(Ag + (size_t)row * 1024 + k0 + dc * 8, &Al[(w * 2 + j) * 64 * 8]);
        }
        for (int j = 0; j < 2; ++j) {
            int c = (w * 2 + j) * 64 + lane;
            int row = c >> 2;
            int dc = (c & 3) ^ (row & 3);
            gld16(Bg + (size_t)row * 1024 + k0 + dc * 8, &Bl[(w * 2 + j) * 64 * 8]);
        }
        __syncthreads();

        bf16x8 af[4], bfr[4];
        for (int i = 0; i < 4; ++i) {
            int r = wr * 64 + i * 16 + lcol;
            af[i] = *(const bf16x8*)&Al[r * 32 + ((quad ^ (r & 3)) * 8)];
        }
        for (int j = 0; j < 4; ++j) {
            int r = wc * 64 + j * 16 + lcol;
            bfr[j] = *(const bf16x8*)&Bl[r * 32 + ((quad ^ (r & 3)) * 8)];
        }
        for (int i = 0; i < 4; ++i)
            for (int j = 0; j < 4; ++j) acc[i][j] = MFMA16(af[i], bfr[j], acc[i][j]);
    }

    // epilogue: scatter to q/k/v head buffers (bf16)
    int col0 = bx * 128 + wc * 64;
    int row0 = by * 128 + wr * 64;
    int seg = col0 >> 10;  // block-uniform: 0=q 1=k 2=v

    for (int i = 0; i < 4; ++i) {
        int m0 = row0 + i * 16 + quad * 4;
        int bb = m0 >> 10, n0 = m0 & 1023;
        for (int j = 0; j < 4; ++j) {
            int o = col0 + j * 16 + lcol;
            if (seg == 0) {
                int hh = o >> 6, d = o & 63;
                float qb = qbias[o];
                for (int r = 0; r < 4; ++r) {
                    float v = (acc[i][j][r] + qb) * 0.125f;
                    qbuf[((size_t)((bb * 16 + hh) * 1024 + n0 + r)) * 64 + d] = (bf16)v;
                }
            } else if (seg == 1) {
                int o2 = o - 1024;
                int hh = o2 >> 6, d = o2 & 63;
                for (int r = 0; r < 4; ++r) {
                    kbuf[((size_t)((bb * 16 + hh) * 1024 + n0 + r)) * 64 + d] = (bf16)acc[i][j][r];
                }
            } else {
                int o2 = o - 2048;
                int hh = o2 >> 6, d = o2 & 63;
                float vbv = vbias[o2];
                bf16x4 pk;
                pk.x = (bf16)(acc[i][j][0] + vbv);
                pk.y = (bf16)(acc[i][j][1] + vbv);
                pk.z = (bf16)(acc[i][j][2] + vbv);
                pk.w = (bf16)(acc[i][j][3] + vbv);
                // vbuf transposed: [b,h,d,n]
                *(bf16x4*)&vbuf[((size_t)((bb * 16 + hh) * 64 + d)) * 1024 + n0] = pk;
            }
        }
    }
}

// ---------------- flash attention ----------------
// One block per (b, h, 64-row q tile); 4 waves, each owns 16 q rows.
// K/Vt tiles (64x64 bf16) staged via global_load_lds with XOR chunk swizzle.
__global__ __launch_bounds__(256) void flash_attn(
    const bf16* __restrict__ qbuf, const bf16* __restrict__ kbuf,
    const bf16* __restrict__ vbuf, const bf16* __restrict__ bias,
    const int* __restrict__ mask, float* __restrict__ out) {
    __shared__ __align__(16) bf16 Kl[64 * 64];
    __shared__ __align__(16) bf16 Vl[64 * 64];
    __shared__ __align__(16) bf16 Pl[64 * 64];

    int bx = blockIdx.x;
    int b = bx & 7;
    int t = bx >> 3;
    int h = t & 15;
    int qt = t >> 4;
    int tid = threadIdx.x, lane = tid & 63, w = tid >> 6;
    int quad = lane >> 4, lcol = lane & 15;

    // Q fragments, held in registers across the whole K loop (scale already folded)
    const bf16* qbase = qbuf + ((size_t)((b * 16 + h) * 1024 + qt * 64 + w * 16)) * 64;
    bf16x8 qf0 = *(const bf16x8*)(qbase + lcol * 64 + quad * 8);
    bf16x8 qf1 = *(const bf16x8*)(qbase + lcol * 64 + 32 + quad * 8);

    const bf16* kb = kbuf + ((size_t)((b * 16 + h) * 1024)) * 64;
    const bf16* vb = vbuf + ((size_t)((b * 16 + h) * 64)) * 1024;  // [d][n]
    const bf16* bb = bias + ((size_t)(h * 1024 + qt * 64 + w * 16)) * 1024;
    const int* mk = mask + b * 1024;

    floatx4 z4 = {0.f, 0.f, 0.f, 0.f};
    float mrun[4], lrun[4];
    floatx4 oacc[4];
    for (int r = 0; r < 4; ++r) { mrun[r] = -1e30f; lrun[r] = 0.f; }
    for (int j = 0; j < 4; ++j) oacc[j] = z4;

    for (int kt = 0; kt < 16; ++kt) {
        int k0 = kt * 64;
        __syncthreads();
        // stage K tile (rows=key, 8 chunks of 8 elems each, swizzled)
        for (int j = 0; j < 2; ++j) {
            int c = (w * 2 + j) * 64 + lane;
            int key = c >> 3;
            int dc = (c & 7) ^ (key & 7);
            gld16(kb + (size_t)(k0 + key) * 64 + dc * 8, &Kl[(w * 2 + j) * 64 * 8]);
        }
        // stage Vt tile (rows=d, cols=key)
        for (int j = 0; j < 2; ++j) {
            int c = (w * 2 + j) * 64 + lane;
            int d = c >> 3;
            int kc = (c & 7) ^ (d & 7);
            gld16(vb + (size_t)d * 1024 + k0 + kc * 8, &Vl[(w * 2 + j) * 64 * 8]);
        }
        __syncthreads();

        // S = Q K^T  (wave strip: 16 q rows x 64 keys)
        floatx4 sacc[4];
        for (int j = 0; j < 4; ++j) sacc[j] = z4;
        for (int j = 0; j < 4; ++j) {
            int key = j * 16 + lcol;
            bf16x8 kf0 = *(const bf16x8*)&Kl[key * 64 + ((quad ^ (key & 7)) * 8)];
            sacc[j] = MFMA16(qf0, kf0, sacc[j]);
            bf16x8 kf1 = *(const bf16x8*)&Kl[key * 64 + (((4 + quad) ^ (key & 7)) * 8)];
            sacc[j] = MFMA16(qf1, kf1, sacc[j]);
        }

        // bias + mask
        float sv[4][4];
        int mv[4];
        for (int j = 0; j < 4; ++j) mv[j] = mk[k0 + j * 16 + lcol];
        for (int j = 0; j < 4; ++j) {
            int colb = k0 + j * 16 + lcol;
            for (int r = 0; r < 4; ++r) {
                float bvl = (float)bb[(size_t)(quad * 4 + r) * 1024 + colb];
                sv[j][r] = mv[j] ? 1e-8f : (sacc[j][r] + bvl);
            }
        }

        // online softmax (per q row; row lives in 16 lanes of this quad-group)
        float rmax[4];
        for (int r = 0; r < 4; ++r)
            rmax[r] = fmaxf(fmaxf(sv[0][r], sv[1][r]), fmaxf(sv[2][r], sv[3][r]));
        for (int d = 1; d < 16; d <<= 1)
            for (int r = 0; r < 4; ++r) rmax[r] = fmaxf(rmax[r], __shfl_xor(rmax[r], d));

        float alpha[4];
        for (int r = 0; r < 4; ++r) {
            float mnew = fmaxf(mrun[r], rmax[r]);
            alpha[r] = __expf(mrun[r] - mnew);
            mrun[r] = mnew;
        }
        float p[4][4];
        for (int j = 0; j < 4; ++j)
            for (int r = 0; r < 4; ++r) p[j][r] = __expf(sv[j][r] - mrun[r]);
        float rsum[4];
        for (int r = 0; r < 4; ++r) rsum[r] = p[0][r] + p[1][r] + p[2][r] + p[3][r];
        for (int d = 1; d < 16; d <<= 1)
            for (int r = 0; r < 4; ++r) rsum[r] += __shfl_xor(rsum[r], d);
        for (int r = 0; r < 4; ++r) lrun[r] = lrun[r] * alpha[r] + rsum[r];
        for (int j = 0; j < 4; ++j)
            for (int r = 0; r < 4; ++r) oacc[j][r] *= alpha[r];

        // P -> LDS (wave-private rows; C-layout -> A-layout transform)
        for (int j = 0; j < 4; ++j)
            for (int r = 0; r < 4; ++r)
                Pl[(size_t)(w * 16 + quad * 4 + r) * 64 + j * 16 + lcol] = (bf16)p[j][r];

        // O += P V  (reads only this wave's P rows; compiler inserts lgkm waits)
        for (int s = 0; s < 2; ++s) {
            bf16x8 pf = *(const bf16x8*)&Pl[(size_t)(w * 16 + lcol) * 64 + s * 32 + quad * 8];
            for (int jd = 0; jd < 4; ++jd) {
                int dd = jd * 16 + lcol;
                bf16x8 vf = *(const bf16x8*)&Vl[dd * 64 + (((s * 4 + quad) ^ (dd & 7)) * 8)];
                oacc[jd] = MFMA16(pf, vf, oacc[jd]);
            }
        }
    }

    // epilogue: out[b, n, h*64+d] = O / l
    for (int jd = 0; jd < 4; ++jd) {
        int d = jd * 16 + lcol;
        for (int r = 0; r < 4; ++r) {
            int n = qt * 64 + w * 16 + quad * 4 + r;
            out[((size_t)(b * 1024 + n)) * 1024 + h * 64 + d] = oacc[jd][r] / lrun[r];
        }
    }
}

// ---------------- launch ----------------
extern "C" void kernel_launch(void* const* d_in, const int* in_sizes, int n_in,
                              void* d_out, int out_size, void* d_ws, size_t ws_size,
                              hipStream_t stream) {
    const float* hs   = (const float*)d_in[0];  // [8,1024,1024]
    const float* qkvw = (const float*)d_in[1];  // [3072,1024]
    const float* qb   = (const float*)d_in[2];  // [1024]
    const float* vbi  = (const float*)d_in[3];  // [1024]
    const float* rel  = (const float*)d_in[4];  // [16,1024,1024]
    const float* rel2 = (const float*)d_in[5];  // [16,1024,1024]
    const int*   msk  = (const int*)d_in[6];    // [8,1024]
    float* out = (float*)d_out;

    char* w = (char*)d_ws;
    bf16* Xb = (bf16*)w;  w += (size_t)8388608 * 2;
    bf16* Wb = (bf16*)w;  w += (size_t)3145728 * 2;
    bf16* Bb = (bf16*)w;  w += (size_t)16777216 * 2;
    bf16* Qb = (bf16*)w;  w += (size_t)8388608 * 2;
    bf16* Kb = (bf16*)w;  w += (size_t)8388608 * 2;
    bf16* Vb = (bf16*)w;  w += (size_t)8388608 * 2;

    cvt_kernel<<<8388608 / 4 / 256, 256, 0, stream>>>(hs, Xb, 8388608 / 4);
    cvt_kernel<<<3145728 / 4 / 256, 256, 0, stream>>>(qkvw, Wb, 3145728 / 4);
    combine_kernel<<<16777216 / 4 / 256, 256, 0, stream>>>(rel, rel2, Bb, 16777216 / 4);
    qkv_gemm<<<dim3(24, 64), 256, 0, stream>>>(Xb, Wb, qb, vbi, Qb, Kb, Vb);
    flash_attn<<<2048, 256, 0, stream>>>(Qb, Kb, Vb, Bb, msk, out);
}